// Round 1
// baseline (89.082 us; speedup 1.0000x reference)
//
#include <hip/hip_runtime.h>

#define BATCH 8
#define ROWS  2048
#define WIDTH 4096
#define COLS  4096
#define KB    1024   // WIDTH / 4 (gating blocks along k)
#define CB    1024   // COLS  / 4 (gating blocks along c)
#define RCH   64     // rows per colsum block

// ---------------------------------------------------------------------------
// Kernel 1: xs[b,k] = sum_r X[b,r,k].  float4-vectorized, split over row
// chunks for occupancy, accumulated with float atomics (xs pre-zeroed).
// grid = (WIDTH/4/256, BATCH, ROWS/RCH) = (4, 8, 32) = 1024 blocks.
// ---------------------------------------------------------------------------
__global__ __launch_bounds__(256) void colsum_kernel(const float4* __restrict__ X,
                                                     float* __restrict__ xs) {
    const int k4 = blockIdx.x * blockDim.x + threadIdx.x;  // k/4 in [0,1024)
    const int b  = blockIdx.y;
    const int r0 = blockIdx.z * RCH;

    const float4* p = X + (size_t)(b * ROWS + r0) * (WIDTH / 4) + k4;
    float ax = 0.f, ay = 0.f, az = 0.f, aw = 0.f;
#pragma unroll 8
    for (int r = 0; r < RCH; ++r) {
        float4 v = p[(size_t)r * (WIDTH / 4)];
        ax += v.x; ay += v.y; az += v.z; aw += v.w;
    }
    float* dst = xs + (size_t)b * WIDTH + 4 * k4;
    atomicAdd(dst + 0, ax);
    atomicAdd(dst + 1, ay);
    atomicAdd(dst + 2, az);
    atomicAdd(dst + 3, aw);
}

// ---------------------------------------------------------------------------
// Kernel 2: per-thread (kb, cb) gated partial:
//   acc = sum_b G[b,kb,cb] * sum_{j<4} xs[b,4kb+j] * W4[4kb+j, cb]
// where W4[k,cb] = sum of W[k, 4cb..4cb+3] (one float4 load).
// Block-tree reduce -> blocksum[block]. grid = (CB/256, KB) = 4096 blocks.
// ---------------------------------------------------------------------------
__global__ __launch_bounds__(256) void gated_reduce_kernel(const float* __restrict__ W,
                                                           const float* __restrict__ G,
                                                           const float* __restrict__ xs,
                                                           float* __restrict__ blocksum) {
    const int cb = blockIdx.x * blockDim.x + threadIdx.x;  // [0, 1024)
    const int kb = blockIdx.y;                             // [0, 1024)

    const float4* Wv = (const float4*)W;  // W row k: float4 index k*CB + cb
    float w4[4];
#pragma unroll
    for (int j = 0; j < 4; ++j) {
        float4 w = Wv[(size_t)(4 * kb + j) * CB + cb];
        w4[j] = (w.x + w.y) + (w.z + w.w);
    }

    float acc = 0.f;
#pragma unroll
    for (int b = 0; b < BATCH; ++b) {
        float inner = 0.f;
#pragma unroll
        for (int j = 0; j < 4; ++j)
            inner += xs[b * WIDTH + 4 * kb + j] * w4[j];
        acc += G[((size_t)b * KB + kb) * CB + cb] * inner;
    }

    __shared__ float red[256];
    red[threadIdx.x] = acc;
    __syncthreads();
    for (int off = 128; off > 0; off >>= 1) {
        if (threadIdx.x < off) red[threadIdx.x] += red[threadIdx.x + off];
        __syncthreads();
    }
    if (threadIdx.x == 0)
        blocksum[blockIdx.y * gridDim.x + blockIdx.x] = red[0];
}

// ---------------------------------------------------------------------------
// Kernel 3: s = sum(blocksum); out[0] = s*s. Single block, deterministic.
// ---------------------------------------------------------------------------
__global__ __launch_bounds__(256) void finalize_kernel(const float* __restrict__ blocksum,
                                                       int n, float* __restrict__ out) {
    float acc = 0.f;
    for (int i = threadIdx.x; i < n; i += 256) acc += blocksum[i];
    __shared__ float red[256];
    red[threadIdx.x] = acc;
    __syncthreads();
    for (int off = 128; off > 0; off >>= 1) {
        if (threadIdx.x < off) red[threadIdx.x] += red[threadIdx.x + off];
        __syncthreads();
    }
    if (threadIdx.x == 0) {
        float s = red[0];
        out[0] = s * s;
    }
}

extern "C" void kernel_launch(void* const* d_in, const int* in_sizes, int n_in,
                              void* d_out, int out_size, void* d_ws, size_t ws_size,
                              hipStream_t stream) {
    const float* X = (const float*)d_in[0];  // (8, 2048, 4096)
    const float* W = (const float*)d_in[1];  // (4096, 4096)
    const float* G = (const float*)d_in[2];  // (8, 1024, 1024)
    float* out = (float*)d_out;              // scalar

    float* xs       = (float*)d_ws;          // 8*4096 floats
    float* blocksum = xs + BATCH * WIDTH;    // 4096 floats
    const int nblocksum = (CB / 256) * KB;   // 4096

    // zero the atomic accumulator region (xs) every call — deterministic
    hipMemsetAsync(d_ws, 0, (size_t)BATCH * WIDTH * sizeof(float), stream);

    dim3 g1(WIDTH / 4 / 256, BATCH, ROWS / RCH);
    colsum_kernel<<<g1, 256, 0, stream>>>((const float4*)X, xs);

    dim3 g2(CB / 256, KB);
    gated_reduce_kernel<<<g2, 256, 0, stream>>>(W, G, xs, blocksum);

    finalize_kernel<<<1, 256, 0, stream>>>(blocksum, nblocksum, out);
}